// Round 8
// baseline (412.872 us; speedup 1.0000x reference)
//
#include <hip/hip_runtime.h>
#include <hip/hip_bf16.h>

#define DEVINL __device__ __forceinline__

constexpr int N  = 50000;
constexpr int E  = 600000;
constexpr int TE = E + N;      // edges + self loops
constexpr int D  = 128;
constexpr int GEMM_ROWS = 128;            // 32 rows per wave (2x16 tiles), 4 waves
constexpr int GEMM_B = (N + GEMM_ROWS - 1) / GEMM_ROWS;  // 391
constexpr int HST_STRIDE = 136;           // ushorts; quad-staggered banks, 16B-aligned

// ---- counting-sort CSR build params (R19) ----
constexpr int NBUCK = (N + 255) >> 8;     // 196 buckets of 256 nodes
constexpr int NSB   = 2 * NBUCK;          // both sides (dst-keyed, src-keyed)
constexpr int CHUNK = 2560;               // edges per count/scatter block
constexpr int EB3   = (TE + CHUNK - 1) / CHUNK;  // 254 (must be <= 256 for 1-block scan)

// ---- fused first-dispatch block roles (R21: cnt + wb3) ----
constexpr int FUSE_CNT = EB3;             // [0,254): edge bucket count
constexpr int FUSE_WB  = FUSE_CNT + 192;  // [254,446): W->bf16 x3

typedef short bf16x8 __attribute__((ext_vector_type(8)));
typedef float f32x4  __attribute__((ext_vector_type(4)));

DEVINL float lrelu(float x, float s) { return x >= 0.f ? x : s * x; }

DEVINL unsigned short f2bf(float f) {   // RNE fp32 -> bf16
    unsigned u = __float_as_uint(f);
    u += 0x7FFFu + ((u >> 16) & 1u);
    return (unsigned short)(u >> 16);
}
DEVINL float bfl(unsigned u) { return __uint_as_float(u << 16); }          // low bf16
DEVINL float bfh(unsigned u) { return __uint_as_float(u & 0xFFFF0000u); }  // high bf16

DEVINL void edge_sd(int e, const int* ei, int& s, int& d) {
    if (e < E) { s = ei[e]; d = ei[E + e]; }
    else       { s = d = e - E; }
}

// ---------- fused: edge bucket-count + W->bf16 (R21) ----------
__global__ __launch_bounds__(256) void k_fused0(const int* __restrict__ ei,
                                                unsigned* __restrict__ hist,   // [EB3][NSB]
                                                const float* __restrict__ W0,
                                                const float* __restrict__ W1,
                                                const float* __restrict__ W2,
                                                unsigned short* __restrict__ Wb) {
    __shared__ unsigned cnt[NSB];   // 1568 B
    int b = blockIdx.x;
    if (b < FUSE_CNT) {
        for (int t = threadIdx.x; t < NSB; t += 256) cnt[t] = 0;
        __syncthreads();
        int base = b * CHUNK;
        for (int i = threadIdx.x; i < CHUNK; i += 256) {
            int e = base + i;
            if (e < TE) {
                int s, d; edge_sd(e, ei, s, d);
                atomicAdd(&cnt[d >> 8], 1u);
                atomicAdd(&cnt[NBUCK + (s >> 8)], 1u);
            }
        }
        __syncthreads();
        unsigned* row = hist + (size_t)b * NSB;
        for (int t = threadIdx.x; t < NSB; t += 256) row[t] = cnt[t];
    } else {
        int bb = b - FUSE_CNT;        // 0..191, 64 per layer
        int l = bb >> 6;
        const float* W = (l == 0) ? W0 : (l == 1) ? W1 : W2;
        int t = (bb & 63) * 256 + threadIdx.x;
        Wb[l * 16384 + t] = f2bf(W[t]);
    }
}

// ---------- MFMA GEMM: H[v,o] = sum_k BN(Xin)[v,k] * W[o,k]  (bf16 in, fp32 acc) ----------
// R20: two 16-row tiles per wave: every B fragment load feeds 2 MFMAs.
__global__ __launch_bounds__(256) void k_gemm(const float* __restrict__ X,
                                              const unsigned short* __restrict__ O16,
                                              const unsigned short* __restrict__ Wb,
                                              unsigned short* __restrict__ Hb16,
                                              const float* __restrict__ att,
                                              float* __restrict__ ai,
                                              float* __restrict__ ajx,
                                              const float* __restrict__ csum,
                                              const float* __restrict__ csq,
                                              const float* __restrict__ g,
                                              const float* __restrict__ be,
                                              int apply_bn) {
    __shared__ unsigned short hst[4][32][HST_STRIDE];   // ~34 KB
    __shared__ float ssl[256];                          // scale[128], shift[128]
    int wave = threadIdx.x >> 6, lane = threadIdx.x & 63;
    int m = lane & 15, quad = lane >> 4;
    int r0 = blockIdx.x * GEMM_ROWS + wave * 32;

    if (apply_bn) {
        if (threadIdx.x < 128) {
            int c = threadIdx.x;
            float mean = csum[c] / (float)N;
            float var  = csq[c] / (float)N - mean * mean;
            float scale = g[c] * rsqrtf(var + 1e-5f);
            ssl[c] = scale;
            ssl[128 + c] = be[c] - mean * scale;
        }
        __syncthreads();
    }

    // ---- A fragments: 2 row-tiles x 4 K-steps ----
    bf16x8 afrag[2][4];
    #pragma unroll
    for (int tile = 0; tile < 2; tile++) {
        int rowA = r0 + tile * 16 + m;
        bool rowok = rowA < N;
        #pragma unroll
        for (int k4 = 0; k4 < 4; k4++) {
            int c0 = k4 * 32 + quad * 8;   // feature column of first element
            float v[8];
            if (rowok) {
                if (apply_bn) {
                    uint4 hu = *(const uint4*)(O16 + (size_t)rowA * D + c0);
                    v[0] = bfl(hu.x); v[1] = bfh(hu.x);
                    v[2] = bfl(hu.y); v[3] = bfh(hu.y);
                    v[4] = bfl(hu.z); v[5] = bfh(hu.z);
                    v[6] = bfl(hu.w); v[7] = bfh(hu.w);
                    #pragma unroll
                    for (int j = 0; j < 8; j++)
                        v[j] = lrelu(v[j] * ssl[c0 + j] + ssl[128 + c0 + j], 0.1f);
                } else {
                    float4 x0 = *(const float4*)(X + (size_t)rowA * D + c0);
                    float4 x1 = *(const float4*)(X + (size_t)rowA * D + c0 + 4);
                    v[0] = x0.x; v[1] = x0.y; v[2] = x0.z; v[3] = x0.w;
                    v[4] = x1.x; v[5] = x1.y; v[6] = x1.z; v[7] = x1.w;
                }
            } else {
                #pragma unroll
                for (int j = 0; j < 8; j++) v[j] = 0.f;
            }
            #pragma unroll
            for (int j = 0; j < 8; j++) afrag[tile][k4][j] = (short)f2bf(v[j]);
        }
    }

    // ---- 8 col-tiles of 16, K=128 via 4 MFMA each, B reused across 2 row-tiles ----
    float pii[2][4] = {{0.f,0.f,0.f,0.f},{0.f,0.f,0.f,0.f}};
    float pjj[2][4] = {{0.f,0.f,0.f,0.f},{0.f,0.f,0.f,0.f}};
    #pragma unroll
    for (int nt = 0; nt < 8; nt++) {
        int n0 = nt * 16;
        f32x4 acc0 = {0.f, 0.f, 0.f, 0.f};
        f32x4 acc1 = {0.f, 0.f, 0.f, 0.f};
        const unsigned short* wrow = Wb + (size_t)(n0 + m) * D + quad * 8;
        #pragma unroll
        for (int k4 = 0; k4 < 4; k4++) {
            bf16x8 bfr = *(const bf16x8*)(wrow + k4 * 32);
            acc0 = __builtin_amdgcn_mfma_f32_16x16x32_bf16(afrag[0][k4], bfr, acc0, 0, 0, 0);
            acc1 = __builtin_amdgcn_mfma_f32_16x16x32_bf16(afrag[1][k4], bfr, acc1, 0, 0, 0);
        }
        float ad = att[n0 + m];
        float as = att[128 + n0 + m];
        #pragma unroll
        for (int i = 0; i < 4; i++) {
            hst[wave][quad * 4 + i][n0 + m]      = f2bf(acc0[i]);
            hst[wave][16 + quad * 4 + i][n0 + m] = f2bf(acc1[i]);
            pii[0][i] += acc0[i] * ad;
            pjj[0][i] += acc0[i] * as;
            pii[1][i] += acc1[i] * ad;
            pjj[1][i] += acc1[i] * as;
        }
    }

    // ---- coalesced H flush: lane reads 16B of a staged row, dwordx4 store ----
    #pragma unroll
    for (int t = 0; t < 8; t++) {
        int r = t * 4 + quad;              // 0..31 within wave tile
        int row = r0 + r;
        int cb = m * 8;                    // ushort col base (16 B)
        uint4 vv = *(const uint4*)&hst[wave][r][cb];
        if (row < N)
            *(uint4*)(Hb16 + (size_t)row * D + cb) = vv;
    }

    // ---- reduce attention dots across the 16 lanes of each quad ----
    #pragma unroll
    for (int mask = 8; mask >= 1; mask >>= 1) {
        #pragma unroll
        for (int tile = 0; tile < 2; tile++) {
            #pragma unroll
            for (int i = 0; i < 4; i++) {
                pii[tile][i] += __shfl_xor(pii[tile][i], mask);
                pjj[tile][i] += __shfl_xor(pjj[tile][i], mask);
            }
        }
    }
    if (m == 0) {
        #pragma unroll
        for (int tile = 0; tile < 2; tile++) {
            #pragma unroll
            for (int i = 0; i < 4; i++) {
                int row = r0 + tile * 16 + quad * 4 + i;
                if (row < N) { ai[row] = pii[tile][i]; ajx[2 * (size_t)row] = pjj[tile][i]; }
            }
        }
    }
}

// ---------- CSR build via 2-level counting sort (R19, consolidated R23) ----------
// R18: global atomic RMWs on gfx950 write ~32B through to HBM regardless of
// scope (measured 4x). LDS atomics only; block-contiguous global writes.
// R23: bscan + boff launches eliminated. Each scatter block recomputes its own
// per-block prefix and the bucket bases by streaming the full hist table
// (254 coalesced row-reads of a 400KB L2-resident array) + in-LDS per-side
// scan. k_csr does the same for its bucket's beg/end. 1-block kernels were
// pure launch-boundary cost. Decoder-M role rides on k_scatter's tail blocks.
__global__ __launch_bounds__(256) void k_scatter(const int* __restrict__ ei,
                                                 const unsigned* __restrict__ hist,
                                                 unsigned* __restrict__ sorted, // [2*TE]
                                                 const float* __restrict__ P1,
                                                 const float* __restrict__ P2,
                                                 float* __restrict__ Mm) {
    __shared__ unsigned pref[NSB];
    __shared__ unsigned tot[NSB];
    __shared__ unsigned bbase[NSB];
    __shared__ unsigned sc[256];
    __shared__ unsigned alloc[NSB];
    __shared__ float trow[128];
    int j = blockIdx.x, t = threadIdx.x;
    if (j >= EB3) {
        // ---- decoder-M role: blocks [EB3, EB3+64) ----
        int bb = j - EB3;
        if (t < 128) {
            int i = bb * 2 + (t >> 6), d = t & 63;   // T rows bb*2, bb*2+1
            float s = 0.f;
            #pragma unroll 8
            for (int k = 0; k < 64; k++) s += P1[i * 64 + k] * P2[k * 64 + d];
            trow[t] = s;
        }
        __syncthreads();
        int tg = bb * 256 + t;
        int jj = tg & 127;
        const float* Tr = trow + (t >> 7) * 64;
        float s = 0.f;
        #pragma unroll 8
        for (int d = 0; d < 64; d++) s += Tr[d] * P1[jj * 64 + d];
        Mm[tg] = s;
        return;
    }
    // ---- stream hist: per-block prefix (rows < j) + column totals ----
    unsigned p0 = 0, p1 = 0, T0 = 0, T1 = 0;
    for (int i = 0; i < EB3; i++) {
        const unsigned* row = hist + (size_t)i * NSB;
        unsigned a = row[t];                              // t < 256 < NSB
        unsigned b = (t + 256 < NSB) ? row[t + 256] : 0;
        T0 += a; T1 += b;
        if (i < j) { p0 += a; p1 += b; }
    }
    pref[t] = p0; tot[t] = T0;
    if (t + 256 < NSB) { pref[t + 256] = p1; tot[t + 256] = T1; }
    __syncthreads();
    // ---- per-side exclusive scan of bucket totals -> bucket bases ----
    for (int side = 0; side < 2; side++) {
        unsigned v = (t < NBUCK) ? tot[side * NBUCK + t] : 0;
        sc[t] = v;
        __syncthreads();
        #pragma unroll
        for (int off = 1; off < 256; off <<= 1) {
            unsigned add = (t >= off) ? sc[t - off] : 0;
            __syncthreads();
            sc[t] += add;
            __syncthreads();
        }
        if (t < NBUCK) bbase[side * NBUCK + t] = sc[t] - v;
        __syncthreads();
    }
    for (int sbt = t; sbt < NSB; sbt += 256) {
        int side = sbt >= NBUCK;
        alloc[sbt] = bbase[sbt] + pref[sbt] + (side ? (unsigned)TE : 0u);
    }
    __syncthreads();
    // ---- scatter ----
    int base = j * CHUNK;
    for (int i = threadIdx.x; i < CHUNK; i += 256) {
        int e = base + i;
        if (e < TE) {
            int s, d; edge_sd(e, ei, s, d);
            unsigned pd = atomicAdd(&alloc[d >> 8], 1u);
            sorted[pd] = ((unsigned)(d & 255) << 16) | (unsigned)s;
            unsigned ps = atomicAdd(&alloc[NBUCK + (s >> 8)], 1u);
            sorted[ps] = ((unsigned)(s & 255) << 16) | (unsigned)d;
        }
    }
}

__global__ __launch_bounds__(256) void k_csr(const unsigned* __restrict__ hist,
                                             const unsigned* __restrict__ sorted,
                                             int* __restrict__ ptrbase,
                                             unsigned short* __restrict__ srcc,
                                             unsigned short* __restrict__ dstc) {
    __shared__ unsigned tot[NSB];
    __shared__ unsigned sc[256];
    __shared__ unsigned cnt[256];
    __shared__ unsigned begend[2];
    int sb = blockIdx.x, t = threadIdx.x;
    int side = sb >= NBUCK;
    int bucket = sb - side * NBUCK;
    // ---- column totals from hist ----
    unsigned T0 = 0, T1 = 0;
    for (int i = 0; i < EB3; i++) {
        const unsigned* row = hist + (size_t)i * NSB;
        T0 += row[t];
        T1 += (t + 256 < NSB) ? row[t + 256] : 0;
    }
    tot[t] = T0;
    if (t + 256 < NSB) tot[t + 256] = T1;
    __syncthreads();
    // ---- own-side inclusive scan -> beg/end of this bucket ----
    unsigned v = (t < NBUCK) ? tot[side * NBUCK + t] : 0;
    sc[t] = v;
    __syncthreads();
    #pragma unroll
    for (int off = 1; off < 256; off <<= 1) {
        unsigned add = (t >= off) ? sc[t - off] : 0;
        __syncthreads();
        sc[t] += add;
        __syncthreads();
    }
    if (t == bucket) { begend[0] = sc[t] - v; begend[1] = sc[t]; }
    __syncthreads();
    unsigned beg = begend[0], end = begend[1];
    const unsigned* srt = sorted + (side ? (size_t)TE : 0);
    unsigned short* out = side ? dstc : srcc;
    int* ptr = ptrbase + (size_t)side * (N + 8);
    // ---- per-node counts within bucket ----
    cnt[t] = 0;
    __syncthreads();
    for (unsigned idx = beg + t; idx < end; idx += 256)
        atomicAdd(&cnt[srt[idx] >> 16], 1u);
    __syncthreads();
    unsigned own = cnt[t];
    sc[t] = own;
    __syncthreads();
    #pragma unroll
    for (int off = 1; off < 256; off <<= 1) {
        unsigned add = (t >= off) ? sc[t - off] : 0;
        __syncthreads();
        sc[t] += add;
        __syncthreads();
    }
    unsigned loc = sc[t] - own;           // exclusive within bucket
    int v2 = (bucket << 8) + t;
    if (v2 < N) ptr[v2] = (int)(beg + loc);
    if (t == 0 && bucket == 0) ptr[N] = TE;
    cnt[t] = beg + loc;                   // reuse as allocator
    __syncthreads();
    for (unsigned idx = beg + t; idx < end; idx += 256) {
        unsigned u = srt[idx];
        unsigned pos = atomicAdd(&cnt[u >> 16], 1u);
        out[pos] = (unsigned short)u;
    }
}

// ---------- softmax denominator: 16-lane group per SRC node, no atomics ----------
__global__ __launch_bounds__(256) void k_den(const int* __restrict__ srcp,
                                             const unsigned short* __restrict__ dstc,
                                             const float* __restrict__ ai,
                                             float* __restrict__ ajx,
                                             float* __restrict__ csumz) {
    if (blockIdx.x == 0) csumz[threadIdx.x] = 0.f;
    int g = threadIdx.x >> 4, l16 = threadIdx.x & 15;
    int v = blockIdx.x * 16 + g;
    if (v >= N) return;
    int beg = srcp[v], end = srcp[v + 1];
    float ajv = ajx[2 * (size_t)v];
    float acc = 0.f;
    for (int idx = beg + l16; idx < end; idx += 16) {
        int d = dstc[idx];
        acc += __expf(lrelu(ai[d] + ajv, 0.2f));
    }
    #pragma unroll
    for (int mask = 8; mask >= 1; mask >>= 1) acc += __shfl_xor(acc, mask);
    if (l16 == 0) ajx[2 * (size_t)v + 1] = 1.0f / (acc + 1e-16f);
}

// ---------- aggregation: wave per dst node, pair-gather, bf16 O output ----------
// R22: tail loops = ONE predicated 8-edge batch (index clamped, weight zeroed).
__global__ __launch_bounds__(256) void k_aggregate(const int* __restrict__ rowp,
                                                   const unsigned short* __restrict__ srcc,
                                                   const float* __restrict__ ai,
                                                   const float2* __restrict__ ajinv,
                                                   const uint2* __restrict__ Hu2, // 4 bf16 per uint2
                                                   const float* __restrict__ bvec,
                                                   unsigned short* __restrict__ O16) {
    int wid = threadIdx.x >> 6, lane = threadIdx.x & 63;
    int h = lane >> 5, l32 = lane & 31;
    int v = blockIdx.x * 4 + wid;
    if (v >= N) return;
    int beg = rowp[v], end = rowp[v + 1];   // non-empty (self loop)
    float aiv = ai[v];
    float a0 = 0.f, a1 = 0.f, a2 = 0.f, a3 = 0.f;
    int idx = beg;
    for (; idx + 8 <= end; idx += 8) {            // full batches: 4 pairs = 8 edges
        int    s[4];
        float2 aw[4];
        uint2  u[4];
        #pragma unroll
        for (int t = 0; t < 4; t++) s[t] = srcc[idx + 2 * t + h];
        #pragma unroll
        for (int t = 0; t < 4; t++) aw[t] = ajinv[s[t]];
        #pragma unroll
        for (int t = 0; t < 4; t++) u[t] = Hu2[(size_t)s[t] * 32 + l32];
        #pragma unroll
        for (int t = 0; t < 4; t++) {
            float w = __expf(lrelu(aiv + aw[t].x, 0.2f)) * aw[t].y;
            a0 += w * bfl(u[t].x);
            a1 += w * bfh(u[t].x);
            a2 += w * bfl(u[t].y);
            a3 += w * bfh(u[t].y);
        }
    }
    int R = end - idx;                            // 0..7 residual edges
    if (R > 0) {                                  // single predicated batch, full MLP
        int    s[4];
        float2 aw[4];
        uint2  u[4];
        #pragma unroll
        for (int t = 0; t < 4; t++) {
            int sl = idx + 2 * t + h;
            s[t] = srcc[sl < end ? sl : beg];     // clamp keeps gather valid
        }
        #pragma unroll
        for (int t = 0; t < 4; t++) aw[t] = ajinv[s[t]];
        #pragma unroll
        for (int t = 0; t < 4; t++) u[t] = Hu2[(size_t)s[t] * 32 + l32];
        #pragma unroll
        for (int t = 0; t < 4; t++) {
            float w = (2 * t + h < R) ? __expf(lrelu(aiv + aw[t].x, 0.2f)) * aw[t].y : 0.f;
            a0 += w * bfl(u[t].x);
            a1 += w * bfh(u[t].x);
            a2 += w * bfl(u[t].y);
            a3 += w * bfh(u[t].y);
        }
    }
    a0 += __shfl_xor(a0, 32);
    a1 += __shfl_xor(a1, 32);
    a2 += __shfl_xor(a2, 32);
    a3 += __shfl_xor(a3, 32);
    if (h == 0) {
        float4 b = ((const float4*)bvec)[l32];
        float o0 = fmaxf(a0 + b.x, 0.f);
        float o1 = fmaxf(a1 + b.y, 0.f);
        float o2 = fmaxf(a2 + b.z, 0.f);
        float o3 = fmaxf(a3 + b.w, 0.f);
        uint2 st;
        st.x = (unsigned)f2bf(o0) | ((unsigned)f2bf(o1) << 16);
        st.y = (unsigned)f2bf(o2) | ((unsigned)f2bf(o3) << 16);
        *(uint2*)(O16 + (size_t)v * D + l32 * 4) = st;
    }
}

// ---------- BN column stats on bf16 O: uint2 per thread (4 cols), LDS reduce ----------
__global__ __launch_bounds__(256) void k_stats(const unsigned short* __restrict__ O16,
                                               float* __restrict__ colsum, float* __restrict__ colsq) {
    int c4 = (threadIdx.x & 31) * 4;   // column base (4 cols per thread)
    int rg = threadIdx.x >> 5;         // row group 0..7
    float s0=0.f,s1=0.f,s2=0.f,s3=0.f,q0=0.f,q1=0.f,q2=0.f,q3=0.f;
    for (int v = blockIdx.x * 8 + rg; v < N; v += gridDim.x * 8) {
        uint2 u = *(const uint2*)(O16 + (size_t)v * D + c4);
        float v0 = bfl(u.x), v1 = bfh(u.x), v2 = bfl(u.y), v3 = bfh(u.y);
        s0 += v0; q0 += v0 * v0;
        s1 += v1; q1 += v1 * v1;
        s2 += v2; q2 += v2 * v2;
        s3 += v3; q3 += v3 * v3;
    }
    __shared__ float ls[8][128], lq[8][128];   // 8 KB
    ls[rg][c4+0]=s0; ls[rg][c4+1]=s1; ls[rg][c4+2]=s2; ls[rg][c4+3]=s3;
    lq[rg][c4+0]=q0; lq[rg][c4+1]=q1; lq[rg][c4+2]=q2; lq[rg][c4+3]=q3;
    __syncthreads();
    if (threadIdx.x < 128) {
        int c = threadIdx.x;
        float s = 0.f, q = 0.f;
        #pragma unroll
        for (int r = 0; r < 8; r++) { s += ls[r][c]; q += lq[r][c]; }
        atomicAdd(colsum + c, s);
        atomicAdd(colsq + c, q);
    }
}

// ---------- decoder prediction ----------
__global__ __launch_bounds__(128) void k_pred(const unsigned short* __restrict__ O16,
                                              const float* __restrict__ csum,
                                              const float* __restrict__ csq,
                                              const float* __restrict__ g,
                                              const float* __restrict__ be,
                                              const int* __restrict__ drug,
                                              const float* __restrict__ M,
                                              float* __restrict__ out) {
    int b = blockIdx.x, i = threadIdx.x;
    __shared__ float av[128], bv[128];
    int ia = drug[b * 2] - 1, ib = drug[b * 2 + 1] - 1;
    float mean = csum[i] / (float)N;
    float var  = csq[i] / (float)N - mean * mean;
    float scale = g[i] * rsqrtf(var + 1e-5f);
    float shift = be[i] - mean * scale;
    float ha = __uint_as_float(((unsigned)O16[(size_t)ia * D + i]) << 16);
    float hb = __uint_as_float(((unsigned)O16[(size_t)ib * D + i]) << 16);
    av[i] = lrelu(ha * scale + shift, 0.1f);
    bv[i] = lrelu(hb * scale + shift, 0.1f);
    __syncthreads();
    const float4* M4  = (const float4*)(M + (size_t)i * 128);
    const float4* bv4 = (const float4*)bv;
    float u = 0.f;
    #pragma unroll 8
    for (int j = 0; j < 32; j++) {
        float4 mv = M4[j];
        float4 bb = bv4[j];
        u += mv.x * bb.x + mv.y * bb.y + mv.z * bb.z + mv.w * bb.w;
    }
    float val = av[i] * u;
    #pragma unroll
    for (int off = 32; off; off >>= 1) val += __shfl_down(val, off);
    __shared__ float red[2];
    if ((i & 63) == 0) red[i >> 6] = val;
    __syncthreads();
    if (i == 0) out[b] = red[0] + red[1];
}

extern "C" void kernel_launch(void* const* d_in, const int* in_sizes, int n_in,
                              void* d_out, int out_size, void* d_ws, size_t ws_size,
                              hipStream_t stream) {
    const float* x    = (const float*)d_in[0];
    const int*   ei   = (const int*)  d_in[1];
    const int*   drug = (const int*)  d_in[2];
    const float* W[3]   = {(const float*)d_in[3], (const float*)d_in[8],  (const float*)d_in[13]};
    const float* att[3] = {(const float*)d_in[4], (const float*)d_in[9],  (const float*)d_in[14]};
    const float* bb[3]  = {(const float*)d_in[5], (const float*)d_in[10], (const float*)d_in[15]};
    const float* gg[3]  = {(const float*)d_in[6], (const float*)d_in[11], (const float*)d_in[16]};
    const float* be[3]  = {(const float*)d_in[7], (const float*)d_in[12], (const float*)d_in[17]};
    const float* P1 = (const float*)d_in[18];
    const float* P2 = (const float*)d_in[19];

    float* ws = (float*)d_ws;
    size_t o_H      = 0;                     // bf16 H: N*128 ushorts = N*64 float slots
    size_t o_O      = o_H + (size_t)N * 64;  // bf16 O: N*128 ushorts = N*64 float slots
    size_t o_ai     = o_O + (size_t)N * 64;
    size_t o_ajinv  = o_ai + N;              // float2 per node: (aj, invden)
    size_t o_colsum = o_ajinv + 2 * (size_t)N;  // 128
    size_t o_colsq  = o_colsum + 128;           // 128
    size_t o_hist   = o_colsq + 128;            // uint [EB3][NSB]
    size_t o_sorted = o_hist + (size_t)EB3 * NSB;     // uint [2*TE]
    size_t o_rowptr = o_sorted + 2 * (size_t)TE;      // int, N+8 (rowp) then srcp contiguous
    size_t o_srcp   = o_rowptr + N + 8;
    size_t o_src    = o_srcp + N + 8;  // ushort, TE  (src per dst-CSR slot)
    size_t o_dstc   = o_src + TE / 2 + 8;  // ushort, TE (dst per src-CSR slot)
    size_t o_Mm     = o_dstc + TE / 2 + 8; // 128*128
    size_t o_Wb     = o_Mm + 128 * 128;// 3*16384 ushorts = 24576 floats

    unsigned short* Hb16 = (unsigned short*)(ws + o_H);
    uint2*          Hu2  = (uint2*)(ws + o_H);
    unsigned short* O16  = (unsigned short*)(ws + o_O);
    float*    ai    = ws + o_ai;
    float*    ajx   = ws + o_ajinv;
    float2*   ajinv = (float2*)(ws + o_ajinv);
    float*    csum  = ws + o_colsum;
    float*    csq   = ws + o_colsq;
    unsigned* hist  = (unsigned*)(ws + o_hist);
    unsigned* sorted= (unsigned*)(ws + o_sorted);
    int*      rowp  = (int*)(ws + o_rowptr);
    int*      srcp  = (int*)(ws + o_srcp);
    unsigned short* srcc = (unsigned short*)(ws + o_src);
    unsigned short* dstc = (unsigned short*)(ws + o_dstc);
    float*    Mm    = ws + o_Mm;
    unsigned short* Wb = (unsigned short*)(ws + o_Wb);

    const int NB4  = (N + 3) / 4;
    const int NB16 = (N + 15) / 16;

    // ---- fused: edge bucket-count + W bf16 (independent, both wide) ----
    k_fused0<<<FUSE_WB, 256, 0, stream>>>(ei, hist, W[0], W[1], W[2], Wb);

    // ---- dual CSR via counting sort: 3 launches total (R23) ----
    k_scatter<<<EB3 + 64, 256, 0, stream>>>(ei, hist, sorted, P1, P2, Mm);
    k_csr    <<<NSB, 256, 0, stream>>>(hist, sorted, rowp, srcc, dstc);

    // ---- 3 GAT layers (no per-layer memsets, no atomics in softmax) ----
    for (int l = 0; l < 3; l++) {
        // gemm reads previous layer's colsum/colsq (l>0); k_den zeroes them after.
        k_gemm<<<GEMM_B, 256, 0, stream>>>(x, O16, Wb + l * 16384, Hb16, att[l],
                                           ai, ajx, csum, csq, gg[l == 0 ? 0 : l - 1],
                                           be[l == 0 ? 0 : l - 1], l > 0 ? 1 : 0);
        k_den<<<NB16, 256, 0, stream>>>(srcp, dstc, ai, ajx, csum);
        k_aggregate<<<NB4, 256, 0, stream>>>(rowp, srcc, ai, ajinv, Hu2, bb[l], O16);
        k_stats<<<256, 256, 0, stream>>>(O16, csum, csq);
    }

    // ---- decoder (BN finalize for layer 3 is inlined in k_pred) ----
    k_pred<<<1024, 128, 0, stream>>>(O16, csum, csq, gg[2], be[2], drug, Mm, (float*)d_out);
}

// Round 9
// 359.748 us; speedup vs baseline: 1.1477x; 1.1477x over previous
//
#include <hip/hip_runtime.h>
#include <hip/hip_bf16.h>

#define DEVINL __device__ __forceinline__

constexpr int N  = 50000;
constexpr int E  = 600000;
constexpr int TE = E + N;      // edges + self loops
constexpr int D  = 128;
constexpr int GEMM_ROWS = 128;            // 32 rows per wave (2x16 tiles), 4 waves
constexpr int GEMM_B = (N + GEMM_ROWS - 1) / GEMM_ROWS;  // 391
constexpr int HST_STRIDE = 136;           // ushorts; quad-staggered banks, 16B-aligned

// ---- counting-sort CSR build params (R19) ----
constexpr int NBUCK = (N + 255) >> 8;     // 196 buckets of 256 nodes
constexpr int NSB   = 2 * NBUCK;          // both sides (dst-keyed, src-keyed)
constexpr int CHUNK = 2560;               // edges per count/scatter block
constexpr int EB3   = (TE + CHUNK - 1) / CHUNK;  // 254 (must be <= 256 for 1-block scan)
constexpr int EB3P  = 256;                // padded stride for pref rows

// ---- fused first-dispatch block roles (R21: cnt + wb3) ----
constexpr int FUSE_CNT = EB3;             // [0,254): edge bucket count
constexpr int FUSE_WB  = FUSE_CNT + 192;  // [254,446): W->bf16 x3

typedef short bf16x8 __attribute__((ext_vector_type(8)));
typedef float f32x4  __attribute__((ext_vector_type(4)));

DEVINL float lrelu(float x, float s) { return x >= 0.f ? x : s * x; }

DEVINL unsigned short f2bf(float f) {   // RNE fp32 -> bf16
    unsigned u = __float_as_uint(f);
    u += 0x7FFFu + ((u >> 16) & 1u);
    return (unsigned short)(u >> 16);
}
DEVINL float bfl(unsigned u) { return __uint_as_float(u << 16); }          // low bf16
DEVINL float bfh(unsigned u) { return __uint_as_float(u & 0xFFFF0000u); }  // high bf16

DEVINL void edge_sd(int e, const int* ei, int& s, int& d) {
    if (e < E) { s = ei[e]; d = ei[E + e]; }
    else       { s = d = e - E; }
}

// ---------- fused: edge bucket-count + W->bf16 (R21) ----------
__global__ __launch_bounds__(256) void k_fused0(const int* __restrict__ ei,
                                                unsigned* __restrict__ hist,   // [EB3][NSB]
                                                const float* __restrict__ W0,
                                                const float* __restrict__ W1,
                                                const float* __restrict__ W2,
                                                unsigned short* __restrict__ Wb) {
    __shared__ unsigned cnt[NSB];   // 1568 B
    int b = blockIdx.x;
    if (b < FUSE_CNT) {
        for (int t = threadIdx.x; t < NSB; t += 256) cnt[t] = 0;
        __syncthreads();
        int base = b * CHUNK;
        for (int i = threadIdx.x; i < CHUNK; i += 256) {
            int e = base + i;
            if (e < TE) {
                int s, d; edge_sd(e, ei, s, d);
                atomicAdd(&cnt[d >> 8], 1u);
                atomicAdd(&cnt[NBUCK + (s >> 8)], 1u);
            }
        }
        __syncthreads();
        unsigned* row = hist + (size_t)b * NSB;
        for (int t = threadIdx.x; t < NSB; t += 256) row[t] = cnt[t];
    } else {
        int bb = b - FUSE_CNT;        // 0..191, 64 per layer
        int l = bb >> 6;
        const float* W = (l == 0) ? W0 : (l == 1) ? W1 : W2;
        int t = (bb & 63) * 256 + threadIdx.x;
        Wb[l * 16384 + t] = f2bf(W[t]);
    }
}

// ---------- MFMA GEMM: H[v,o] = sum_k BN(Xin)[v,k] * W[o,k]  (bf16 in, fp32 acc) ----------
// R20: two 16-row tiles per wave: every B fragment load feeds 2 MFMAs.
__global__ __launch_bounds__(256) void k_gemm(const float* __restrict__ X,
                                              const unsigned short* __restrict__ O16,
                                              const unsigned short* __restrict__ Wb,
                                              unsigned short* __restrict__ Hb16,
                                              const float* __restrict__ att,
                                              float* __restrict__ ai,
                                              float* __restrict__ ajx,
                                              const float* __restrict__ csum,
                                              const float* __restrict__ csq,
                                              const float* __restrict__ g,
                                              const float* __restrict__ be,
                                              int apply_bn) {
    __shared__ unsigned short hst[4][32][HST_STRIDE];   // ~34 KB
    __shared__ float ssl[256];                          // scale[128], shift[128]
    int wave = threadIdx.x >> 6, lane = threadIdx.x & 63;
    int m = lane & 15, quad = lane >> 4;
    int r0 = blockIdx.x * GEMM_ROWS + wave * 32;

    if (apply_bn) {
        if (threadIdx.x < 128) {
            int c = threadIdx.x;
            float mean = csum[c] / (float)N;
            float var  = csq[c] / (float)N - mean * mean;
            float scale = g[c] * rsqrtf(var + 1e-5f);
            ssl[c] = scale;
            ssl[128 + c] = be[c] - mean * scale;
        }
        __syncthreads();
    }

    // ---- A fragments: 2 row-tiles x 4 K-steps ----
    bf16x8 afrag[2][4];
    #pragma unroll
    for (int tile = 0; tile < 2; tile++) {
        int rowA = r0 + tile * 16 + m;
        bool rowok = rowA < N;
        #pragma unroll
        for (int k4 = 0; k4 < 4; k4++) {
            int c0 = k4 * 32 + quad * 8;   // feature column of first element
            float v[8];
            if (rowok) {
                if (apply_bn) {
                    uint4 hu = *(const uint4*)(O16 + (size_t)rowA * D + c0);
                    v[0] = bfl(hu.x); v[1] = bfh(hu.x);
                    v[2] = bfl(hu.y); v[3] = bfh(hu.y);
                    v[4] = bfl(hu.z); v[5] = bfh(hu.z);
                    v[6] = bfl(hu.w); v[7] = bfh(hu.w);
                    #pragma unroll
                    for (int j = 0; j < 8; j++)
                        v[j] = lrelu(v[j] * ssl[c0 + j] + ssl[128 + c0 + j], 0.1f);
                } else {
                    float4 x0 = *(const float4*)(X + (size_t)rowA * D + c0);
                    float4 x1 = *(const float4*)(X + (size_t)rowA * D + c0 + 4);
                    v[0] = x0.x; v[1] = x0.y; v[2] = x0.z; v[3] = x0.w;
                    v[4] = x1.x; v[5] = x1.y; v[6] = x1.z; v[7] = x1.w;
                }
            } else {
                #pragma unroll
                for (int j = 0; j < 8; j++) v[j] = 0.f;
            }
            #pragma unroll
            for (int j = 0; j < 8; j++) afrag[tile][k4][j] = (short)f2bf(v[j]);
        }
    }

    // ---- 8 col-tiles of 16, K=128 via 4 MFMA each, B reused across 2 row-tiles ----
    float pii[2][4] = {{0.f,0.f,0.f,0.f},{0.f,0.f,0.f,0.f}};
    float pjj[2][4] = {{0.f,0.f,0.f,0.f},{0.f,0.f,0.f,0.f}};
    #pragma unroll
    for (int nt = 0; nt < 8; nt++) {
        int n0 = nt * 16;
        f32x4 acc0 = {0.f, 0.f, 0.f, 0.f};
        f32x4 acc1 = {0.f, 0.f, 0.f, 0.f};
        const unsigned short* wrow = Wb + (size_t)(n0 + m) * D + quad * 8;
        #pragma unroll
        for (int k4 = 0; k4 < 4; k4++) {
            bf16x8 bfr = *(const bf16x8*)(wrow + k4 * 32);
            acc0 = __builtin_amdgcn_mfma_f32_16x16x32_bf16(afrag[0][k4], bfr, acc0, 0, 0, 0);
            acc1 = __builtin_amdgcn_mfma_f32_16x16x32_bf16(afrag[1][k4], bfr, acc1, 0, 0, 0);
        }
        float ad = att[n0 + m];
        float as = att[128 + n0 + m];
        #pragma unroll
        for (int i = 0; i < 4; i++) {
            hst[wave][quad * 4 + i][n0 + m]      = f2bf(acc0[i]);
            hst[wave][16 + quad * 4 + i][n0 + m] = f2bf(acc1[i]);
            pii[0][i] += acc0[i] * ad;
            pjj[0][i] += acc0[i] * as;
            pii[1][i] += acc1[i] * ad;
            pjj[1][i] += acc1[i] * as;
        }
    }

    // ---- coalesced H flush: lane reads 16B of a staged row, dwordx4 store ----
    #pragma unroll
    for (int t = 0; t < 8; t++) {
        int r = t * 4 + quad;              // 0..31 within wave tile
        int row = r0 + r;
        int cb = m * 8;                    // ushort col base (16 B)
        uint4 vv = *(const uint4*)&hst[wave][r][cb];
        if (row < N)
            *(uint4*)(Hb16 + (size_t)row * D + cb) = vv;
    }

    // ---- reduce attention dots across the 16 lanes of each quad ----
    #pragma unroll
    for (int mask = 8; mask >= 1; mask >>= 1) {
        #pragma unroll
        for (int tile = 0; tile < 2; tile++) {
            #pragma unroll
            for (int i = 0; i < 4; i++) {
                pii[tile][i] += __shfl_xor(pii[tile][i], mask);
                pjj[tile][i] += __shfl_xor(pjj[tile][i], mask);
            }
        }
    }
    if (m == 0) {
        #pragma unroll
        for (int tile = 0; tile < 2; tile++) {
            #pragma unroll
            for (int i = 0; i < 4; i++) {
                int row = r0 + tile * 16 + quad * 4 + i;
                if (row < N) { ai[row] = pii[tile][i]; ajx[2 * (size_t)row] = pjj[tile][i]; }
            }
        }
    }
}

// ---------- CSR build via 2-level counting sort (R19) ----------
// R18: global atomic RMWs on gfx950 write ~32B through to HBM regardless of
// scope (measured 4x). LDS atomics only; block-contiguous global writes.
// R21: blocks [NSB, NSB+64) carry the decoder-M role at full parallelism.
// R23 post-mortem: streaming the full 400KB hist per block (serial 254-iter
// loop) cost 49us — NEVER trade parallel work for a per-block serial stream.
// R24: k_boff eliminated correctly — scatter/csr read only btot (1.6KB,
// L2-hit) and scan it in LDS (parallel, ~1us).
__global__ __launch_bounds__(256) void k_bscan(const unsigned* __restrict__ hist,
                                               unsigned* __restrict__ pref,   // [NSB][EB3P]
                                               unsigned* __restrict__ btot,   // [NSB]
                                               const float* __restrict__ P1,
                                               const float* __restrict__ P2,
                                               float* __restrict__ Mm) {
    __shared__ unsigned sc[256];
    __shared__ float trow[128];
    int sb = blockIdx.x, t = threadIdx.x;
    if (sb >= NSB) {
        int bb = sb - NSB;            // 0..63 -> M elements [bb*256, bb*256+256)
        if (t < 128) {
            int i = bb * 2 + (t >> 6), d = t & 63;   // T rows bb*2, bb*2+1
            float s = 0.f;
            #pragma unroll 8
            for (int k = 0; k < 64; k++) s += P1[i * 64 + k] * P2[k * 64 + d];
            trow[t] = s;
        }
        __syncthreads();
        int tg = bb * 256 + t;
        int j = tg & 127;
        const float* Tr = trow + (t >> 7) * 64;
        float s = 0.f;
        #pragma unroll 8
        for (int d = 0; d < 64; d++) s += Tr[d] * P1[j * 64 + d];
        Mm[tg] = s;
        return;
    }
    unsigned v = (t < EB3) ? hist[(size_t)t * NSB + sb] : 0;
    sc[t] = v;
    __syncthreads();
    #pragma unroll
    for (int off = 1; off < 256; off <<= 1) {
        unsigned add = (t >= off) ? sc[t - off] : 0;
        __syncthreads();
        sc[t] += add;
        __syncthreads();
    }
    if (t < EB3) pref[(size_t)sb * EB3P + t] = sc[t] - v;   // exclusive
    if (t == EB3 - 1) btot[sb] = sc[t];
}

__global__ __launch_bounds__(256) void k_scatter(const int* __restrict__ ei,
                                                 const unsigned* __restrict__ pref,
                                                 const unsigned* __restrict__ btot,
                                                 unsigned* __restrict__ sorted) { // [2*TE]
    __shared__ unsigned sc[256];
    __shared__ unsigned bbase[NSB];
    __shared__ unsigned alloc[NSB];
    int j = blockIdx.x, t = threadIdx.x;
    // ---- per-side exclusive scan of btot (1.6KB, L2-hit) -> bucket bases ----
    for (int side = 0; side < 2; side++) {
        unsigned v = (t < NBUCK) ? btot[side * NBUCK + t] : 0;
        sc[t] = v;
        __syncthreads();
        #pragma unroll
        for (int off = 1; off < 256; off <<= 1) {
            unsigned add = (t >= off) ? sc[t - off] : 0;
            __syncthreads();
            sc[t] += add;
            __syncthreads();
        }
        if (t < NBUCK) bbase[side * NBUCK + t] = sc[t] - v;
        __syncthreads();
    }
    for (int sbt = t; sbt < NSB; sbt += 256) {
        int side = sbt >= NBUCK;
        alloc[sbt] = bbase[sbt] + pref[(size_t)sbt * EB3P + j]
                   + (side ? (unsigned)TE : 0u);
    }
    __syncthreads();
    int base = j * CHUNK;
    for (int i = threadIdx.x; i < CHUNK; i += 256) {
        int e = base + i;
        if (e < TE) {
            int s, d; edge_sd(e, ei, s, d);
            unsigned pd = atomicAdd(&alloc[d >> 8], 1u);
            sorted[pd] = ((unsigned)(d & 255) << 16) | (unsigned)s;
            unsigned ps = atomicAdd(&alloc[NBUCK + (s >> 8)], 1u);
            sorted[ps] = ((unsigned)(s & 255) << 16) | (unsigned)d;
        }
    }
}

__global__ __launch_bounds__(256) void k_csr(const unsigned* __restrict__ btot,
                                             const unsigned* __restrict__ sorted,
                                             int* __restrict__ ptrbase,
                                             unsigned short* __restrict__ srcc,
                                             unsigned short* __restrict__ dstc) {
    __shared__ unsigned sc[256];
    __shared__ unsigned cnt[256];
    __shared__ unsigned begend[2];
    int sb = blockIdx.x, t = threadIdx.x;
    int side = sb >= NBUCK;
    int bucket = sb - side * NBUCK;
    // ---- own-side inclusive scan of btot -> beg/end of this bucket ----
    unsigned v = (t < NBUCK) ? btot[side * NBUCK + t] : 0;
    sc[t] = v;
    __syncthreads();
    #pragma unroll
    for (int off = 1; off < 256; off <<= 1) {
        unsigned add = (t >= off) ? sc[t - off] : 0;
        __syncthreads();
        sc[t] += add;
        __syncthreads();
    }
    if (t == bucket) { begend[0] = sc[t] - v; begend[1] = sc[t]; }
    __syncthreads();
    unsigned beg = begend[0], end = begend[1];
    const unsigned* srt = sorted + (side ? (size_t)TE : 0);
    unsigned short* out = side ? dstc : srcc;
    int* ptr = ptrbase + (size_t)side * (N + 8);
    cnt[t] = 0;
    __syncthreads();
    for (unsigned idx = beg + t; idx < end; idx += 256)
        atomicAdd(&cnt[srt[idx] >> 16], 1u);
    __syncthreads();
    unsigned own = cnt[t];
    sc[t] = own;
    __syncthreads();
    #pragma unroll
    for (int off = 1; off < 256; off <<= 1) {
        unsigned add = (t >= off) ? sc[t - off] : 0;
        __syncthreads();
        sc[t] += add;
        __syncthreads();
    }
    unsigned loc = sc[t] - own;           // exclusive within bucket
    int v2 = (bucket << 8) + t;
    if (v2 < N) ptr[v2] = (int)(beg + loc);
    if (t == 0 && bucket == 0) ptr[N] = TE;
    cnt[t] = beg + loc;                   // reuse as allocator
    __syncthreads();
    for (unsigned idx = beg + t; idx < end; idx += 256) {
        unsigned u = srt[idx];
        unsigned pos = atomicAdd(&cnt[u >> 16], 1u);
        out[pos] = (unsigned short)u;
    }
}

// ---------- softmax denominator: 16-lane group per SRC node, no atomics ----------
__global__ __launch_bounds__(256) void k_den(const int* __restrict__ srcp,
                                             const unsigned short* __restrict__ dstc,
                                             const float* __restrict__ ai,
                                             float* __restrict__ ajx,
                                             float* __restrict__ csumz) {
    if (blockIdx.x == 0) csumz[threadIdx.x] = 0.f;
    int g = threadIdx.x >> 4, l16 = threadIdx.x & 15;
    int v = blockIdx.x * 16 + g;
    if (v >= N) return;
    int beg = srcp[v], end = srcp[v + 1];
    float ajv = ajx[2 * (size_t)v];
    float acc = 0.f;
    for (int idx = beg + l16; idx < end; idx += 16) {
        int d = dstc[idx];
        acc += __expf(lrelu(ai[d] + ajv, 0.2f));
    }
    #pragma unroll
    for (int mask = 8; mask >= 1; mask >>= 1) acc += __shfl_xor(acc, mask);
    if (l16 == 0) ajx[2 * (size_t)v + 1] = 1.0f / (acc + 1e-16f);
}

// ---------- aggregation: wave per dst node, pair-gather, bf16 O output ----------
// R22: tail loops = ONE predicated 8-edge batch (index clamped, weight zeroed).
__global__ __launch_bounds__(256) void k_aggregate(const int* __restrict__ rowp,
                                                   const unsigned short* __restrict__ srcc,
                                                   const float* __restrict__ ai,
                                                   const float2* __restrict__ ajinv,
                                                   const uint2* __restrict__ Hu2, // 4 bf16 per uint2
                                                   const float* __restrict__ bvec,
                                                   unsigned short* __restrict__ O16) {
    int wid = threadIdx.x >> 6, lane = threadIdx.x & 63;
    int h = lane >> 5, l32 = lane & 31;
    int v = blockIdx.x * 4 + wid;
    if (v >= N) return;
    int beg = rowp[v], end = rowp[v + 1];   // non-empty (self loop)
    float aiv = ai[v];
    float a0 = 0.f, a1 = 0.f, a2 = 0.f, a3 = 0.f;
    int idx = beg;
    for (; idx + 8 <= end; idx += 8) {            // full batches: 4 pairs = 8 edges
        int    s[4];
        float2 aw[4];
        uint2  u[4];
        #pragma unroll
        for (int t = 0; t < 4; t++) s[t] = srcc[idx + 2 * t + h];
        #pragma unroll
        for (int t = 0; t < 4; t++) aw[t] = ajinv[s[t]];
        #pragma unroll
        for (int t = 0; t < 4; t++) u[t] = Hu2[(size_t)s[t] * 32 + l32];
        #pragma unroll
        for (int t = 0; t < 4; t++) {
            float w = __expf(lrelu(aiv + aw[t].x, 0.2f)) * aw[t].y;
            a0 += w * bfl(u[t].x);
            a1 += w * bfh(u[t].x);
            a2 += w * bfl(u[t].y);
            a3 += w * bfh(u[t].y);
        }
    }
    int R = end - idx;                            // 0..7 residual edges
    if (R > 0) {                                  // single predicated batch, full MLP
        int    s[4];
        float2 aw[4];
        uint2  u[4];
        #pragma unroll
        for (int t = 0; t < 4; t++) {
            int sl = idx + 2 * t + h;
            s[t] = srcc[sl < end ? sl : beg];     // clamp keeps gather valid
        }
        #pragma unroll
        for (int t = 0; t < 4; t++) aw[t] = ajinv[s[t]];
        #pragma unroll
        for (int t = 0; t < 4; t++) u[t] = Hu2[(size_t)s[t] * 32 + l32];
        #pragma unroll
        for (int t = 0; t < 4; t++) {
            float w = (2 * t + h < R) ? __expf(lrelu(aiv + aw[t].x, 0.2f)) * aw[t].y : 0.f;
            a0 += w * bfl(u[t].x);
            a1 += w * bfh(u[t].x);
            a2 += w * bfl(u[t].y);
            a3 += w * bfh(u[t].y);
        }
    }
    a0 += __shfl_xor(a0, 32);
    a1 += __shfl_xor(a1, 32);
    a2 += __shfl_xor(a2, 32);
    a3 += __shfl_xor(a3, 32);
    if (h == 0) {
        float4 b = ((const float4*)bvec)[l32];
        float o0 = fmaxf(a0 + b.x, 0.f);
        float o1 = fmaxf(a1 + b.y, 0.f);
        float o2 = fmaxf(a2 + b.z, 0.f);
        float o3 = fmaxf(a3 + b.w, 0.f);
        uint2 st;
        st.x = (unsigned)f2bf(o0) | ((unsigned)f2bf(o1) << 16);
        st.y = (unsigned)f2bf(o2) | ((unsigned)f2bf(o3) << 16);
        *(uint2*)(O16 + (size_t)v * D + l32 * 4) = st;
    }
}

// ---------- BN column stats on bf16 O: uint2 per thread (4 cols), LDS reduce ----------
__global__ __launch_bounds__(256) void k_stats(const unsigned short* __restrict__ O16,
                                               float* __restrict__ colsum, float* __restrict__ colsq) {
    int c4 = (threadIdx.x & 31) * 4;   // column base (4 cols per thread)
    int rg = threadIdx.x >> 5;         // row group 0..7
    float s0=0.f,s1=0.f,s2=0.f,s3=0.f,q0=0.f,q1=0.f,q2=0.f,q3=0.f;
    for (int v = blockIdx.x * 8 + rg; v < N; v += gridDim.x * 8) {
        uint2 u = *(const uint2*)(O16 + (size_t)v * D + c4);
        float v0 = bfl(u.x), v1 = bfh(u.x), v2 = bfl(u.y), v3 = bfh(u.y);
        s0 += v0; q0 += v0 * v0;
        s1 += v1; q1 += v1 * v1;
        s2 += v2; q2 += v2 * v2;
        s3 += v3; q3 += v3 * v3;
    }
    __shared__ float ls[8][128], lq[8][128];   // 8 KB
    ls[rg][c4+0]=s0; ls[rg][c4+1]=s1; ls[rg][c4+2]=s2; ls[rg][c4+3]=s3;
    lq[rg][c4+0]=q0; lq[rg][c4+1]=q1; lq[rg][c4+2]=q2; lq[rg][c4+3]=q3;
    __syncthreads();
    if (threadIdx.x < 128) {
        int c = threadIdx.x;
        float s = 0.f, q = 0.f;
        #pragma unroll
        for (int r = 0; r < 8; r++) { s += ls[r][c]; q += lq[r][c]; }
        atomicAdd(colsum + c, s);
        atomicAdd(colsq + c, q);
    }
}

// ---------- decoder prediction: 4 drug pairs per block (R24: M traffic /4) ----------
__global__ __launch_bounds__(128) void k_pred(const unsigned short* __restrict__ O16,
                                              const float* __restrict__ csum,
                                              const float* __restrict__ csq,
                                              const float* __restrict__ g,
                                              const float* __restrict__ be,
                                              const int* __restrict__ drug,
                                              const float* __restrict__ M,
                                              float* __restrict__ out) {
    int b4 = blockIdx.x, i = threadIdx.x;   // block handles pairs 4*b4 .. 4*b4+3
    __shared__ float av[4][128], bv[4][128];
    float mean = csum[i] / (float)N;
    float var  = csq[i] / (float)N - mean * mean;
    float scale = g[i] * rsqrtf(var + 1e-5f);
    float shift = be[i] - mean * scale;
    #pragma unroll
    for (int p = 0; p < 4; p++) {
        int b = b4 * 4 + p;
        int ia = drug[b * 2] - 1, ib = drug[b * 2 + 1] - 1;
        float ha = __uint_as_float(((unsigned)O16[(size_t)ia * D + i]) << 16);
        float hb = __uint_as_float(((unsigned)O16[(size_t)ib * D + i]) << 16);
        av[p][i] = lrelu(ha * scale + shift, 0.1f);
        bv[p][i] = lrelu(hb * scale + shift, 0.1f);
    }
    __syncthreads();
    const float4* M4 = (const float4*)(M + (size_t)i * 128);
    float u0 = 0.f, u1 = 0.f, u2 = 0.f, u3 = 0.f;
    #pragma unroll 4
    for (int j = 0; j < 32; j++) {
        float4 mv = M4[j];
        float4 b0 = ((const float4*)bv[0])[j];
        float4 b1 = ((const float4*)bv[1])[j];
        float4 b2 = ((const float4*)bv[2])[j];
        float4 b3 = ((const float4*)bv[3])[j];
        u0 += mv.x * b0.x + mv.y * b0.y + mv.z * b0.z + mv.w * b0.w;
        u1 += mv.x * b1.x + mv.y * b1.y + mv.z * b1.z + mv.w * b1.w;
        u2 += mv.x * b2.x + mv.y * b2.y + mv.z * b2.z + mv.w * b2.w;
        u3 += mv.x * b3.x + mv.y * b3.y + mv.z * b3.z + mv.w * b3.w;
    }
    float val[4] = {av[0][i] * u0, av[1][i] * u1, av[2][i] * u2, av[3][i] * u3};
    __shared__ float red[4][2];
    #pragma unroll
    for (int p = 0; p < 4; p++) {
        float x = val[p];
        #pragma unroll
        for (int off = 32; off; off >>= 1) x += __shfl_down(x, off);
        if ((i & 63) == 0) red[p][i >> 6] = x;
    }
    __syncthreads();
    if (i < 4) out[b4 * 4 + i] = red[i][0] + red[i][1];
}

extern "C" void kernel_launch(void* const* d_in, const int* in_sizes, int n_in,
                              void* d_out, int out_size, void* d_ws, size_t ws_size,
                              hipStream_t stream) {
    const float* x    = (const float*)d_in[0];
    const int*   ei   = (const int*)  d_in[1];
    const int*   drug = (const int*)  d_in[2];
    const float* W[3]   = {(const float*)d_in[3], (const float*)d_in[8],  (const float*)d_in[13]};
    const float* att[3] = {(const float*)d_in[4], (const float*)d_in[9],  (const float*)d_in[14]};
    const float* bb[3]  = {(const float*)d_in[5], (const float*)d_in[10], (const float*)d_in[15]};
    const float* gg[3]  = {(const float*)d_in[6], (const float*)d_in[11], (const float*)d_in[16]};
    const float* be[3]  = {(const float*)d_in[7], (const float*)d_in[12], (const float*)d_in[17]};
    const float* P1 = (const float*)d_in[18];
    const float* P2 = (const float*)d_in[19];

    float* ws = (float*)d_ws;
    size_t o_H      = 0;                     // bf16 H: N*128 ushorts = N*64 float slots
    size_t o_O      = o_H + (size_t)N * 64;  // bf16 O: N*128 ushorts = N*64 float slots
    size_t o_ai     = o_O + (size_t)N * 64;
    size_t o_ajinv  = o_ai + N;              // float2 per node: (aj, invden)
    size_t o_colsum = o_ajinv + 2 * (size_t)N;  // 128
    size_t o_colsq  = o_colsum + 128;           // 128
    size_t o_hist   = o_colsq + 128;            // uint [EB3][NSB]
    size_t o_pref   = o_hist + (size_t)EB3 * NSB;     // uint [NSB][EB3P]
    size_t o_btot   = o_pref + (size_t)NSB * EB3P;    // uint [NSB] (pad 512)
    size_t o_sorted = o_btot + 512;                   // uint [2*TE]
    size_t o_rowptr = o_sorted + 2 * (size_t)TE;      // int, N+8 (rowp) then srcp contiguous
    size_t o_srcp   = o_rowptr + N + 8;
    size_t o_src    = o_srcp + N + 8;  // ushort, TE  (src per dst-CSR slot)
    size_t o_dstc   = o_src + TE / 2 + 8;  // ushort, TE (dst per src-CSR slot)
    size_t o_Mm     = o_dstc + TE / 2 + 8; // 128*128
    size_t o_Wb     = o_Mm + 128 * 128;// 3*16384 ushorts = 24576 floats

    unsigned short* Hb16 = (unsigned short*)(ws + o_H);
    uint2*          Hu2  = (uint2*)(ws + o_H);
    unsigned short* O16  = (unsigned short*)(ws + o_O);
    float*    ai    = ws + o_ai;
    float*    ajx   = ws + o_ajinv;
    float2*   ajinv = (float2*)(ws + o_ajinv);
    float*    csum  = ws + o_colsum;
    float*    csq   = ws + o_colsq;
    unsigned* hist  = (unsigned*)(ws + o_hist);
    unsigned* pref  = (unsigned*)(ws + o_pref);
    unsigned* btot  = (unsigned*)(ws + o_btot);
    unsigned* sorted= (unsigned*)(ws + o_sorted);
    int*      rowp  = (int*)(ws + o_rowptr);
    int*      srcp  = (int*)(ws + o_srcp);
    unsigned short* srcc = (unsigned short*)(ws + o_src);
    unsigned short* dstc = (unsigned short*)(ws + o_dstc);
    float*    Mm    = ws + o_Mm;
    unsigned short* Wb = (unsigned short*)(ws + o_Wb);

    const int NB4  = (N + 3) / 4;
    const int NB16 = (N + 15) / 16;

    // ---- fused: edge bucket-count + W bf16 (independent, both wide) ----
    k_fused0<<<FUSE_WB, 256, 0, stream>>>(ei, hist, W[0], W[1], W[2], Wb);

    // ---- dual CSR via counting sort (+ decoder-M role riding on k_bscan) ----
    k_bscan  <<<NSB + 64, 256, 0, stream>>>(hist, pref, btot, P1, P2, Mm);
    k_scatter<<<EB3, 256, 0, stream>>>(ei, pref, btot, sorted);
    k_csr    <<<NSB, 256, 0, stream>>>(btot, sorted, rowp, srcc, dstc);

    // ---- 3 GAT layers (no per-layer memsets, no atomics in softmax) ----
    for (int l = 0; l < 3; l++) {
        // gemm reads previous layer's colsum/colsq (l>0); k_den zeroes them after.
        k_gemm<<<GEMM_B, 256, 0, stream>>>(x, O16, Wb + l * 16384, Hb16, att[l],
                                           ai, ajx, csum, csq, gg[l == 0 ? 0 : l - 1],
                                           be[l == 0 ? 0 : l - 1], l > 0 ? 1 : 0);
        k_den<<<NB16, 256, 0, stream>>>(srcp, dstc, ai, ajx, csum);
        k_aggregate<<<NB4, 256, 0, stream>>>(rowp, srcc, ai, ajinv, Hu2, bb[l], O16);
        k_stats<<<256, 256, 0, stream>>>(O16, csum, csq);
    }

    // ---- decoder (BN finalize for layer 3 is inlined in k_pred) ----
    k_pred<<<256, 128, 0, stream>>>(O16, csum, csq, gg[2], be[2], drug, Mm, (float*)d_out);
}

// Round 10
// 357.993 us; speedup vs baseline: 1.1533x; 1.0049x over previous
//
#include <hip/hip_runtime.h>
#include <hip/hip_bf16.h>

#define DEVINL __device__ __forceinline__

constexpr int N  = 50000;
constexpr int E  = 600000;
constexpr int TE = E + N;      // edges + self loops
constexpr int D  = 128;
constexpr int GEMM_ROWS = 128;            // 32 rows per wave (2x16 tiles), 4 waves
constexpr int GEMM_B = (N + GEMM_ROWS - 1) / GEMM_ROWS;  // 391
constexpr int HST_STRIDE = 136;           // ushorts; quad-staggered banks, 16B-aligned

// ---- counting-sort CSR build params (R19) ----
constexpr int NBUCK = (N + 255) >> 8;     // 196 buckets of 256 nodes
constexpr int NSB   = 2 * NBUCK;          // both sides (dst-keyed, src-keyed)
constexpr int CHUNK = 2560;               // edges per count/scatter block
constexpr int EB3   = (TE + CHUNK - 1) / CHUNK;  // 254 (must be <= 256 for 1-block scan)
constexpr int EB3P  = 256;                // padded stride for pref rows

// ---- fused first-dispatch block roles (R21: cnt + wb3) ----
constexpr int FUSE_CNT = EB3;             // [0,254): edge bucket count
constexpr int FUSE_WB  = FUSE_CNT + 192;  // [254,446): W->bf16 x3

typedef short bf16x8 __attribute__((ext_vector_type(8)));
typedef float f32x4  __attribute__((ext_vector_type(4)));

DEVINL float lrelu(float x, float s) { return x >= 0.f ? x : s * x; }

DEVINL unsigned short f2bf(float f) {   // RNE fp32 -> bf16
    unsigned u = __float_as_uint(f);
    u += 0x7FFFu + ((u >> 16) & 1u);
    return (unsigned short)(u >> 16);
}
DEVINL float bfl(unsigned u) { return __uint_as_float(u << 16); }          // low bf16
DEVINL float bfh(unsigned u) { return __uint_as_float(u & 0xFFFF0000u); }  // high bf16

DEVINL void edge_sd(int e, const int* ei, int& s, int& d) {
    if (e < E) { s = ei[e]; d = ei[E + e]; }
    else       { s = d = e - E; }
}

// ---------- fused: edge bucket-count + W->bf16 (R21) ----------
__global__ __launch_bounds__(256) void k_fused0(const int* __restrict__ ei,
                                                unsigned* __restrict__ hist,   // [EB3][NSB]
                                                const float* __restrict__ W0,
                                                const float* __restrict__ W1,
                                                const float* __restrict__ W2,
                                                unsigned short* __restrict__ Wb) {
    __shared__ unsigned cnt[NSB];   // 1568 B
    int b = blockIdx.x;
    if (b < FUSE_CNT) {
        for (int t = threadIdx.x; t < NSB; t += 256) cnt[t] = 0;
        __syncthreads();
        int base = b * CHUNK;
        for (int i = threadIdx.x; i < CHUNK; i += 256) {
            int e = base + i;
            if (e < TE) {
                int s, d; edge_sd(e, ei, s, d);
                atomicAdd(&cnt[d >> 8], 1u);
                atomicAdd(&cnt[NBUCK + (s >> 8)], 1u);
            }
        }
        __syncthreads();
        unsigned* row = hist + (size_t)b * NSB;
        for (int t = threadIdx.x; t < NSB; t += 256) row[t] = cnt[t];
    } else {
        int bb = b - FUSE_CNT;        // 0..191, 64 per layer
        int l = bb >> 6;
        const float* W = (l == 0) ? W0 : (l == 1) ? W1 : W2;
        int t = (bb & 63) * 256 + threadIdx.x;
        Wb[l * 16384 + t] = f2bf(W[t]);
    }
}

// ---------- MFMA GEMM body: H[v,o] = sum_k BN(Xin)[v,k] * W[o,k] ----------
// R20: two 16-row tiles per wave: every B fragment load feeds 2 MFMAs.
// R25: body extracted so layer-0 (apply_bn=0, independent of the CSR build)
// can ride on the k_bscan dispatch at its original parallelism.
DEVINL void gemm_body(int blk,
                      const float* __restrict__ X,
                      const unsigned short* __restrict__ O16,
                      const unsigned short* __restrict__ Wb,
                      unsigned short* __restrict__ Hb16,
                      const float* __restrict__ att,
                      float* __restrict__ ai,
                      float* __restrict__ ajx,
                      const float* __restrict__ csum,
                      const float* __restrict__ csq,
                      const float* __restrict__ g,
                      const float* __restrict__ be,
                      int apply_bn) {
    __shared__ unsigned short hst[4][32][HST_STRIDE];   // ~34 KB
    __shared__ float ssl[256];                          // scale[128], shift[128]
    int wave = threadIdx.x >> 6, lane = threadIdx.x & 63;
    int m = lane & 15, quad = lane >> 4;
    int r0 = blk * GEMM_ROWS + wave * 32;

    if (apply_bn) {
        if (threadIdx.x < 128) {
            int c = threadIdx.x;
            float mean = csum[c] / (float)N;
            float var  = csq[c] / (float)N - mean * mean;
            float scale = g[c] * rsqrtf(var + 1e-5f);
            ssl[c] = scale;
            ssl[128 + c] = be[c] - mean * scale;
        }
        __syncthreads();
    }

    // ---- A fragments: 2 row-tiles x 4 K-steps ----
    bf16x8 afrag[2][4];
    #pragma unroll
    for (int tile = 0; tile < 2; tile++) {
        int rowA = r0 + tile * 16 + m;
        bool rowok = rowA < N;
        #pragma unroll
        for (int k4 = 0; k4 < 4; k4++) {
            int c0 = k4 * 32 + quad * 8;   // feature column of first element
            float v[8];
            if (rowok) {
                if (apply_bn) {
                    uint4 hu = *(const uint4*)(O16 + (size_t)rowA * D + c0);
                    v[0] = bfl(hu.x); v[1] = bfh(hu.x);
                    v[2] = bfl(hu.y); v[3] = bfh(hu.y);
                    v[4] = bfl(hu.z); v[5] = bfh(hu.z);
                    v[6] = bfl(hu.w); v[7] = bfh(hu.w);
                    #pragma unroll
                    for (int j = 0; j < 8; j++)
                        v[j] = lrelu(v[j] * ssl[c0 + j] + ssl[128 + c0 + j], 0.1f);
                } else {
                    float4 x0 = *(const float4*)(X + (size_t)rowA * D + c0);
                    float4 x1 = *(const float4*)(X + (size_t)rowA * D + c0 + 4);
                    v[0] = x0.x; v[1] = x0.y; v[2] = x0.z; v[3] = x0.w;
                    v[4] = x1.x; v[5] = x1.y; v[6] = x1.z; v[7] = x1.w;
                }
            } else {
                #pragma unroll
                for (int j = 0; j < 8; j++) v[j] = 0.f;
            }
            #pragma unroll
            for (int j = 0; j < 8; j++) afrag[tile][k4][j] = (short)f2bf(v[j]);
        }
    }

    // ---- 8 col-tiles of 16, K=128 via 4 MFMA each, B reused across 2 row-tiles ----
    float pii[2][4] = {{0.f,0.f,0.f,0.f},{0.f,0.f,0.f,0.f}};
    float pjj[2][4] = {{0.f,0.f,0.f,0.f},{0.f,0.f,0.f,0.f}};
    #pragma unroll
    for (int nt = 0; nt < 8; nt++) {
        int n0 = nt * 16;
        f32x4 acc0 = {0.f, 0.f, 0.f, 0.f};
        f32x4 acc1 = {0.f, 0.f, 0.f, 0.f};
        const unsigned short* wrow = Wb + (size_t)(n0 + m) * D + quad * 8;
        #pragma unroll
        for (int k4 = 0; k4 < 4; k4++) {
            bf16x8 bfr = *(const bf16x8*)(wrow + k4 * 32);
            acc0 = __builtin_amdgcn_mfma_f32_16x16x32_bf16(afrag[0][k4], bfr, acc0, 0, 0, 0);
            acc1 = __builtin_amdgcn_mfma_f32_16x16x32_bf16(afrag[1][k4], bfr, acc1, 0, 0, 0);
        }
        float ad = att[n0 + m];
        float as = att[128 + n0 + m];
        #pragma unroll
        for (int i = 0; i < 4; i++) {
            hst[wave][quad * 4 + i][n0 + m]      = f2bf(acc0[i]);
            hst[wave][16 + quad * 4 + i][n0 + m] = f2bf(acc1[i]);
            pii[0][i] += acc0[i] * ad;
            pjj[0][i] += acc0[i] * as;
            pii[1][i] += acc1[i] * ad;
            pjj[1][i] += acc1[i] * as;
        }
    }

    // ---- coalesced H flush: lane reads 16B of a staged row, dwordx4 store ----
    #pragma unroll
    for (int t = 0; t < 8; t++) {
        int r = t * 4 + quad;              // 0..31 within wave tile
        int row = r0 + r;
        int cb = m * 8;                    // ushort col base (16 B)
        uint4 vv = *(const uint4*)&hst[wave][r][cb];
        if (row < N)
            *(uint4*)(Hb16 + (size_t)row * D + cb) = vv;
    }

    // ---- reduce attention dots across the 16 lanes of each quad ----
    #pragma unroll
    for (int mask = 8; mask >= 1; mask >>= 1) {
        #pragma unroll
        for (int tile = 0; tile < 2; tile++) {
            #pragma unroll
            for (int i = 0; i < 4; i++) {
                pii[tile][i] += __shfl_xor(pii[tile][i], mask);
                pjj[tile][i] += __shfl_xor(pjj[tile][i], mask);
            }
        }
    }
    if (m == 0) {
        #pragma unroll
        for (int tile = 0; tile < 2; tile++) {
            #pragma unroll
            for (int i = 0; i < 4; i++) {
                int row = r0 + tile * 16 + quad * 4 + i;
                if (row < N) { ai[row] = pii[tile][i]; ajx[2 * (size_t)row] = pjj[tile][i]; }
            }
        }
    }
}

__global__ __launch_bounds__(256) void k_gemm(const float* __restrict__ X,
                                              const unsigned short* __restrict__ O16,
                                              const unsigned short* __restrict__ Wb,
                                              unsigned short* __restrict__ Hb16,
                                              const float* __restrict__ att,
                                              float* __restrict__ ai,
                                              float* __restrict__ ajx,
                                              const float* __restrict__ csum,
                                              const float* __restrict__ csq,
                                              const float* __restrict__ g,
                                              const float* __restrict__ be,
                                              int apply_bn) {
    gemm_body(blockIdx.x, X, O16, Wb, Hb16, att, ai, ajx, csum, csq, g, be, apply_bn);
}

// ---------- CSR build via 2-level counting sort (R19) ----------
// R18: global atomic RMWs on gfx950 write ~32B through to HBM regardless of
// scope (measured 4x). LDS atomics only; block-contiguous global writes.
// R23 post-mortem: NEVER trade parallel work for a per-block serial stream.
// R24: boff eliminated — scatter/csr scan btot (1.6KB, L2-hit) in LDS.
// R25: blocks [NSB,NSB+64) = decoder-M role; [NSB+64, +GEMM_B) = layer-0 gemm
// (depends only on Wb from k_fused0 — overlaps with the scan at full
// parallelism; R20/R23 lesson: fused work must keep its original parallelism).
__global__ __launch_bounds__(256) void k_bscan(const unsigned* __restrict__ hist,
                                               unsigned* __restrict__ pref,   // [NSB][EB3P]
                                               unsigned* __restrict__ btot,   // [NSB]
                                               const float* __restrict__ P1,
                                               const float* __restrict__ P2,
                                               float* __restrict__ Mm,
                                               const float* __restrict__ X,
                                               const unsigned short* __restrict__ Wb,
                                               unsigned short* __restrict__ Hb16,
                                               const float* __restrict__ att0,
                                               float* __restrict__ ai,
                                               float* __restrict__ ajx) {
    __shared__ unsigned sc[256];
    __shared__ float trow[128];
    int sb = blockIdx.x, t = threadIdx.x;
    if (sb >= NSB + 64) {
        // ---- layer-0 GEMM role (apply_bn=0) ----
        gemm_body(sb - NSB - 64, X, nullptr, Wb, Hb16, att0, ai, ajx,
                  nullptr, nullptr, nullptr, nullptr, 0);
        return;
    }
    if (sb >= NSB) {
        int bb = sb - NSB;            // 0..63 -> M elements [bb*256, bb*256+256)
        if (t < 128) {
            int i = bb * 2 + (t >> 6), d = t & 63;   // T rows bb*2, bb*2+1
            float s = 0.f;
            #pragma unroll 8
            for (int k = 0; k < 64; k++) s += P1[i * 64 + k] * P2[k * 64 + d];
            trow[t] = s;
        }
        __syncthreads();
        int tg = bb * 256 + t;
        int j = tg & 127;
        const float* Tr = trow + (t >> 7) * 64;
        float s = 0.f;
        #pragma unroll 8
        for (int d = 0; d < 64; d++) s += Tr[d] * P1[j * 64 + d];
        Mm[tg] = s;
        return;
    }
    unsigned v = (t < EB3) ? hist[(size_t)t * NSB + sb] : 0;
    sc[t] = v;
    __syncthreads();
    #pragma unroll
    for (int off = 1; off < 256; off <<= 1) {
        unsigned add = (t >= off) ? sc[t - off] : 0;
        __syncthreads();
        sc[t] += add;
        __syncthreads();
    }
    if (t < EB3) pref[(size_t)sb * EB3P + t] = sc[t] - v;   // exclusive
    if (t == EB3 - 1) btot[sb] = sc[t];
}

__global__ __launch_bounds__(256) void k_scatter(const int* __restrict__ ei,
                                                 const unsigned* __restrict__ pref,
                                                 const unsigned* __restrict__ btot,
                                                 unsigned* __restrict__ sorted) { // [2*TE]
    __shared__ unsigned sc[256];
    __shared__ unsigned bbase[NSB];
    __shared__ unsigned alloc[NSB];
    int j = blockIdx.x, t = threadIdx.x;
    // ---- per-side exclusive scan of btot (1.6KB, L2-hit) -> bucket bases ----
    for (int side = 0; side < 2; side++) {
        unsigned v = (t < NBUCK) ? btot[side * NBUCK + t] : 0;
        sc[t] = v;
        __syncthreads();
        #pragma unroll
        for (int off = 1; off < 256; off <<= 1) {
            unsigned add = (t >= off) ? sc[t - off] : 0;
            __syncthreads();
            sc[t] += add;
            __syncthreads();
        }
        if (t < NBUCK) bbase[side * NBUCK + t] = sc[t] - v;
        __syncthreads();
    }
    for (int sbt = t; sbt < NSB; sbt += 256) {
        int side = sbt >= NBUCK;
        alloc[sbt] = bbase[sbt] + pref[(size_t)sbt * EB3P + j]
                   + (side ? (unsigned)TE : 0u);
    }
    __syncthreads();
    int base = j * CHUNK;
    for (int i = threadIdx.x; i < CHUNK; i += 256) {
        int e = base + i;
        if (e < TE) {
            int s, d; edge_sd(e, ei, s, d);
            unsigned pd = atomicAdd(&alloc[d >> 8], 1u);
            sorted[pd] = ((unsigned)(d & 255) << 16) | (unsigned)s;
            unsigned ps = atomicAdd(&alloc[NBUCK + (s >> 8)], 1u);
            sorted[ps] = ((unsigned)(s & 255) << 16) | (unsigned)d;
        }
    }
}

__global__ __launch_bounds__(256) void k_csr(const unsigned* __restrict__ btot,
                                             const unsigned* __restrict__ sorted,
                                             int* __restrict__ ptrbase,
                                             unsigned short* __restrict__ srcc,
                                             unsigned short* __restrict__ dstc) {
    __shared__ unsigned sc[256];
    __shared__ unsigned cnt[256];
    __shared__ unsigned begend[2];
    int sb = blockIdx.x, t = threadIdx.x;
    int side = sb >= NBUCK;
    int bucket = sb - side * NBUCK;
    // ---- own-side inclusive scan of btot -> beg/end of this bucket ----
    unsigned v = (t < NBUCK) ? btot[side * NBUCK + t] : 0;
    sc[t] = v;
    __syncthreads();
    #pragma unroll
    for (int off = 1; off < 256; off <<= 1) {
        unsigned add = (t >= off) ? sc[t - off] : 0;
        __syncthreads();
        sc[t] += add;
        __syncthreads();
    }
    if (t == bucket) { begend[0] = sc[t] - v; begend[1] = sc[t]; }
    __syncthreads();
    unsigned beg = begend[0], end = begend[1];
    const unsigned* srt = sorted + (side ? (size_t)TE : 0);
    unsigned short* out = side ? dstc : srcc;
    int* ptr = ptrbase + (size_t)side * (N + 8);
    cnt[t] = 0;
    __syncthreads();
    for (unsigned idx = beg + t; idx < end; idx += 256)
        atomicAdd(&cnt[srt[idx] >> 16], 1u);
    __syncthreads();
    unsigned own = cnt[t];
    sc[t] = own;
    __syncthreads();
    #pragma unroll
    for (int off = 1; off < 256; off <<= 1) {
        unsigned add = (t >= off) ? sc[t - off] : 0;
        __syncthreads();
        sc[t] += add;
        __syncthreads();
    }
    unsigned loc = sc[t] - own;           // exclusive within bucket
    int v2 = (bucket << 8) + t;
    if (v2 < N) ptr[v2] = (int)(beg + loc);
    if (t == 0 && bucket == 0) ptr[N] = TE;
    cnt[t] = beg + loc;                   // reuse as allocator
    __syncthreads();
    for (unsigned idx = beg + t; idx < end; idx += 256) {
        unsigned u = srt[idx];
        unsigned pos = atomicAdd(&cnt[u >> 16], 1u);
        out[pos] = (unsigned short)u;
    }
}

// ---------- softmax denominator: 16-lane group per SRC node, no atomics ----------
__global__ __launch_bounds__(256) void k_den(const int* __restrict__ srcp,
                                             const unsigned short* __restrict__ dstc,
                                             const float* __restrict__ ai,
                                             float* __restrict__ ajx,
                                             float* __restrict__ csumz) {
    if (blockIdx.x == 0) csumz[threadIdx.x] = 0.f;
    int g = threadIdx.x >> 4, l16 = threadIdx.x & 15;
    int v = blockIdx.x * 16 + g;
    if (v >= N) return;
    int beg = srcp[v], end = srcp[v + 1];
    float ajv = ajx[2 * (size_t)v];
    float acc = 0.f;
    for (int idx = beg + l16; idx < end; idx += 16) {
        int d = dstc[idx];
        acc += __expf(lrelu(ai[d] + ajv, 0.2f));
    }
    #pragma unroll
    for (int mask = 8; mask >= 1; mask >>= 1) acc += __shfl_xor(acc, mask);
    if (l16 == 0) ajx[2 * (size_t)v + 1] = 1.0f / (acc + 1e-16f);
}

// ---------- aggregation: wave per dst node, pair-gather, bf16 O output ----------
// R22: tail loops = ONE predicated 8-edge batch (index clamped, weight zeroed).
__global__ __launch_bounds__(256) void k_aggregate(const int* __restrict__ rowp,
                                                   const unsigned short* __restrict__ srcc,
                                                   const float* __restrict__ ai,
                                                   const float2* __restrict__ ajinv,
                                                   const uint2* __restrict__ Hu2, // 4 bf16 per uint2
                                                   const float* __restrict__ bvec,
                                                   unsigned short* __restrict__ O16) {
    int wid = threadIdx.x >> 6, lane = threadIdx.x & 63;
    int h = lane >> 5, l32 = lane & 31;
    int v = blockIdx.x * 4 + wid;
    if (v >= N) return;
    int beg = rowp[v], end = rowp[v + 1];   // non-empty (self loop)
    float aiv = ai[v];
    float a0 = 0.f, a1 = 0.f, a2 = 0.f, a3 = 0.f;
    int idx = beg;
    for (; idx + 8 <= end; idx += 8) {            // full batches: 4 pairs = 8 edges
        int    s[4];
        float2 aw[4];
        uint2  u[4];
        #pragma unroll
        for (int t = 0; t < 4; t++) s[t] = srcc[idx + 2 * t + h];
        #pragma unroll
        for (int t = 0; t < 4; t++) aw[t] = ajinv[s[t]];
        #pragma unroll
        for (int t = 0; t < 4; t++) u[t] = Hu2[(size_t)s[t] * 32 + l32];
        #pragma unroll
        for (int t = 0; t < 4; t++) {
            float w = __expf(lrelu(aiv + aw[t].x, 0.2f)) * aw[t].y;
            a0 += w * bfl(u[t].x);
            a1 += w * bfh(u[t].x);
            a2 += w * bfl(u[t].y);
            a3 += w * bfh(u[t].y);
        }
    }
    int R = end - idx;                            // 0..7 residual edges
    if (R > 0) {                                  // single predicated batch, full MLP
        int    s[4];
        float2 aw[4];
        uint2  u[4];
        #pragma unroll
        for (int t = 0; t < 4; t++) {
            int sl = idx + 2 * t + h;
            s[t] = srcc[sl < end ? sl : beg];     // clamp keeps gather valid
        }
        #pragma unroll
        for (int t = 0; t < 4; t++) aw[t] = ajinv[s[t]];
        #pragma unroll
        for (int t = 0; t < 4; t++) u[t] = Hu2[(size_t)s[t] * 32 + l32];
        #pragma unroll
        for (int t = 0; t < 4; t++) {
            float w = (2 * t + h < R) ? __expf(lrelu(aiv + aw[t].x, 0.2f)) * aw[t].y : 0.f;
            a0 += w * bfl(u[t].x);
            a1 += w * bfh(u[t].x);
            a2 += w * bfl(u[t].y);
            a3 += w * bfh(u[t].y);
        }
    }
    a0 += __shfl_xor(a0, 32);
    a1 += __shfl_xor(a1, 32);
    a2 += __shfl_xor(a2, 32);
    a3 += __shfl_xor(a3, 32);
    if (h == 0) {
        float4 b = ((const float4*)bvec)[l32];
        float o0 = fmaxf(a0 + b.x, 0.f);
        float o1 = fmaxf(a1 + b.y, 0.f);
        float o2 = fmaxf(a2 + b.z, 0.f);
        float o3 = fmaxf(a3 + b.w, 0.f);
        uint2 st;
        st.x = (unsigned)f2bf(o0) | ((unsigned)f2bf(o1) << 16);
        st.y = (unsigned)f2bf(o2) | ((unsigned)f2bf(o3) << 16);
        *(uint2*)(O16 + (size_t)v * D + l32 * 4) = st;
    }
}

// ---------- BN column stats on bf16 O: uint2 per thread (4 cols), LDS reduce ----------
__global__ __launch_bounds__(256) void k_stats(const unsigned short* __restrict__ O16,
                                               float* __restrict__ colsum, float* __restrict__ colsq) {
    int c4 = (threadIdx.x & 31) * 4;   // column base (4 cols per thread)
    int rg = threadIdx.x >> 5;         // row group 0..7
    float s0=0.f,s1=0.f,s2=0.f,s3=0.f,q0=0.f,q1=0.f,q2=0.f,q3=0.f;
    for (int v = blockIdx.x * 8 + rg; v < N; v += gridDim.x * 8) {
        uint2 u = *(const uint2*)(O16 + (size_t)v * D + c4);
        float v0 = bfl(u.x), v1 = bfh(u.x), v2 = bfl(u.y), v3 = bfh(u.y);
        s0 += v0; q0 += v0 * v0;
        s1 += v1; q1 += v1 * v1;
        s2 += v2; q2 += v2 * v2;
        s3 += v3; q3 += v3 * v3;
    }
    __shared__ float ls[8][128], lq[8][128];   // 8 KB
    ls[rg][c4+0]=s0; ls[rg][c4+1]=s1; ls[rg][c4+2]=s2; ls[rg][c4+3]=s3;
    lq[rg][c4+0]=q0; lq[rg][c4+1]=q1; lq[rg][c4+2]=q2; lq[rg][c4+3]=q3;
    __syncthreads();
    if (threadIdx.x < 128) {
        int c = threadIdx.x;
        float s = 0.f, q = 0.f;
        #pragma unroll
        for (int r = 0; r < 8; r++) { s += ls[r][c]; q += lq[r][c]; }
        atomicAdd(colsum + c, s);
        atomicAdd(colsq + c, q);
    }
}

// ---------- decoder prediction: 8 drug pairs per block (R25: M traffic /8) ----------
__global__ __launch_bounds__(128) void k_pred(const unsigned short* __restrict__ O16,
                                              const float* __restrict__ csum,
                                              const float* __restrict__ csq,
                                              const float* __restrict__ g,
                                              const float* __restrict__ be,
                                              const int* __restrict__ drug,
                                              const float* __restrict__ M,
                                              float* __restrict__ out) {
    int b8 = blockIdx.x, i = threadIdx.x;   // block handles pairs 8*b8 .. 8*b8+7
    __shared__ float av[8][128], bv[8][128];
    float mean = csum[i] / (float)N;
    float var  = csq[i] / (float)N - mean * mean;
    float scale = g[i] * rsqrtf(var + 1e-5f);
    float shift = be[i] - mean * scale;
    #pragma unroll
    for (int p = 0; p < 8; p++) {
        int b = b8 * 8 + p;
        int ia = drug[b * 2] - 1, ib = drug[b * 2 + 1] - 1;
        float ha = __uint_as_float(((unsigned)O16[(size_t)ia * D + i]) << 16);
        float hb = __uint_as_float(((unsigned)O16[(size_t)ib * D + i]) << 16);
        av[p][i] = lrelu(ha * scale + shift, 0.1f);
        bv[p][i] = lrelu(hb * scale + shift, 0.1f);
    }
    __syncthreads();
    const float4* M4 = (const float4*)(M + (size_t)i * 128);
    float u[8] = {0.f,0.f,0.f,0.f,0.f,0.f,0.f,0.f};
    #pragma unroll 2
    for (int j = 0; j < 32; j++) {
        float4 mv = M4[j];
        #pragma unroll
        for (int p = 0; p < 8; p++) {
            float4 bb = ((const float4*)bv[p])[j];
            u[p] += mv.x * bb.x + mv.y * bb.y + mv.z * bb.z + mv.w * bb.w;
        }
    }
    __shared__ float red[8][2];
    #pragma unroll
    for (int p = 0; p < 8; p++) {
        float x = av[p][i] * u[p];
        #pragma unroll
        for (int off = 32; off; off >>= 1) x += __shfl_down(x, off);
        if ((i & 63) == 0) red[p][i >> 6] = x;
    }
    __syncthreads();
    if (i < 8) out[b8 * 8 + i] = red[i][0] + red[i][1];
}

extern "C" void kernel_launch(void* const* d_in, const int* in_sizes, int n_in,
                              void* d_out, int out_size, void* d_ws, size_t ws_size,
                              hipStream_t stream) {
    const float* x    = (const float*)d_in[0];
    const int*   ei   = (const int*)  d_in[1];
    const int*   drug = (const int*)  d_in[2];
    const float* W[3]   = {(const float*)d_in[3], (const float*)d_in[8],  (const float*)d_in[13]};
    const float* att[3] = {(const float*)d_in[4], (const float*)d_in[9],  (const float*)d_in[14]};
    const float* bb[3]  = {(const float*)d_in[5], (const float*)d_in[10], (const float*)d_in[15]};
    const float* gg[3]  = {(const float*)d_in[6], (const float*)d_in[11], (const float*)d_in[16]};
    const float* be[3]  = {(const float*)d_in[7], (const float*)d_in[12], (const float*)d_in[17]};
    const float* P1 = (const float*)d_in[18];
    const float* P2 = (const float*)d_in[19];

    float* ws = (float*)d_ws;
    size_t o_H      = 0;                     // bf16 H: N*128 ushorts = N*64 float slots
    size_t o_O      = o_H + (size_t)N * 64;  // bf16 O: N*128 ushorts = N*64 float slots
    size_t o_ai     = o_O + (size_t)N * 64;
    size_t o_ajinv  = o_ai + N;              // float2 per node: (aj, invden)
    size_t o_colsum = o_ajinv + 2 * (size_t)N;  // 128
    size_t o_colsq  = o_colsum + 128;           // 128
    size_t o_hist   = o_colsq + 128;            // uint [EB3][NSB]
    size_t o_pref   = o_hist + (size_t)EB3 * NSB;     // uint [NSB][EB3P]
    size_t o_btot   = o_pref + (size_t)NSB * EB3P;    // uint [NSB] (pad 512)
    size_t o_sorted = o_btot + 512;                   // uint [2*TE]
    size_t o_rowptr = o_sorted + 2 * (size_t)TE;      // int, N+8 (rowp) then srcp contiguous
    size_t o_srcp   = o_rowptr + N + 8;
    size_t o_src    = o_srcp + N + 8;  // ushort, TE  (src per dst-CSR slot)
    size_t o_dstc   = o_src + TE / 2 + 8;  // ushort, TE (dst per src-CSR slot)
    size_t o_Mm     = o_dstc + TE / 2 + 8; // 128*128
    size_t o_Wb     = o_Mm + 128 * 128;// 3*16384 ushorts = 24576 floats

    unsigned short* Hb16 = (unsigned short*)(ws + o_H);
    uint2*          Hu2  = (uint2*)(ws + o_H);
    unsigned short* O16  = (unsigned short*)(ws + o_O);
    float*    ai    = ws + o_ai;
    float*    ajx   = ws + o_ajinv;
    float2*   ajinv = (float2*)(ws + o_ajinv);
    float*    csum  = ws + o_colsum;
    float*    csq   = ws + o_colsq;
    unsigned* hist  = (unsigned*)(ws + o_hist);
    unsigned* pref  = (unsigned*)(ws + o_pref);
    unsigned* btot  = (unsigned*)(ws + o_btot);
    unsigned* sorted= (unsigned*)(ws + o_sorted);
    int*      rowp  = (int*)(ws + o_rowptr);
    int*      srcp  = (int*)(ws + o_srcp);
    unsigned short* srcc = (unsigned short*)(ws + o_src);
    unsigned short* dstc = (unsigned short*)(ws + o_dstc);
    float*    Mm    = ws + o_Mm;
    unsigned short* Wb = (unsigned short*)(ws + o_Wb);

    const int NB4  = (N + 3) / 4;
    const int NB16 = (N + 15) / 16;

    // ---- fused: edge bucket-count + W bf16 (independent, both wide) ----
    k_fused0<<<FUSE_WB, 256, 0, stream>>>(ei, hist, W[0], W[1], W[2], Wb);

    // ---- CSR scan + decoder-M + LAYER-0 GEMM in one dispatch (R25) ----
    k_bscan<<<NSB + 64 + GEMM_B, 256, 0, stream>>>(hist, pref, btot, P1, P2, Mm,
                                                   x, Wb, Hb16, att[0], ai, ajx);
    k_scatter<<<EB3, 256, 0, stream>>>(ei, pref, btot, sorted);
    k_csr    <<<NSB, 256, 0, stream>>>(btot, sorted, rowp, srcc, dstc);

    // ---- 3 GAT layers (layer-0 gemm already done in k_bscan) ----
    for (int l = 0; l < 3; l++) {
        if (l > 0)
            k_gemm<<<GEMM_B, 256, 0, stream>>>(x, O16, Wb + l * 16384, Hb16, att[l],
                                               ai, ajx, csum, csq, gg[l - 1],
                                               be[l - 1], 1);
        k_den<<<NB16, 256, 0, stream>>>(srcp, dstc, ai, ajx, csum);
        k_aggregate<<<NB4, 256, 0, stream>>>(rowp, srcc, ai, ajinv, Hu2, bb[l], O16);
        k_stats<<<256, 256, 0, stream>>>(O16, csum, csq);
    }

    // ---- decoder (BN finalize for layer 3 is inlined in k_pred) ----
    k_pred<<<128, 128, 0, stream>>>(O16, csum, csq, gg[2], be[2], drug, Mm, (float*)d_out);
}